// Round 1
// baseline (678.090 us; speedup 1.0000x reference)
//
#include <hip/hip_runtime.h>
#include <math.h>

#define N_NODES 1024
#define HDIM    128

// One block per node i. 256 threads = 8 groups of 32 lanes; each group
// streams one active edge-embedding row (512 B, float4-coalesced) per step.
__global__ __launch_bounds__(256) void motif_gru_kernel(
    const float* __restrict__ nf,     // [N, H]
    const int*   __restrict__ adj,    // [N, N]
    const float* __restrict__ T,      // [N*N, H]
    const float* __restrict__ w_ih,   // [3H, H]
    const float* __restrict__ w_hh,   // [3H, H]
    const float* __restrict__ b_ih,   // [3H]
    const float* __restrict__ b_hh,   // [3H]
    float*       __restrict__ out)    // [N, H]
{
    const int i   = blockIdx.x;
    const int tid = threadIdx.x;

    __shared__ int   s_list[N_NODES];   // compacted active-j list
    __shared__ int   s_cnt;
    __shared__ float s_red[8][HDIM];    // per-group partial sums
    __shared__ float s_agg[HDIM];
    __shared__ float s_nfi[HDIM];
    __shared__ float s_gi[3 * HDIM];
    __shared__ float s_gh[3 * HDIM];

    if (tid == 0) s_cnt = 0;
    __syncthreads();

    // ---- Phase 1: compact active neighbor list (skip adj==0 rows entirely)
    const int* adj_row = adj + (size_t)i * N_NODES;
    #pragma unroll
    for (int jj = 0; jj < N_NODES / 256; ++jj) {
        int j = tid + jj * 256;
        if (adj_row[j] != 0) {
            int pos = atomicAdd(&s_cnt, 1);
            s_list[pos] = j;
        }
    }
    if (tid < HDIM) s_nfi[tid] = nf[(size_t)i * HDIM + tid];
    __syncthreads();
    const int cnt = s_cnt;

    // ---- Phase 2: agg[i,h] = sum_{active j} nf[j,h] * T[i,j,h]
    const int g    = tid >> 5;   // group 0..7
    const int lane = tid & 31;   // lane within group; 4 floats each -> 128

    const float4* Tv  = reinterpret_cast<const float4*>(T);
    const float4* nfv = reinterpret_cast<const float4*>(nf);
    const size_t rowbase = (size_t)i * N_NODES;

    float4 acc = make_float4(0.f, 0.f, 0.f, 0.f);

    int base = 0;
    for (; base + 16 <= cnt; base += 16) {           // 2-deep unroll: 2 rows/group in flight
        int j0 = s_list[base + g];
        int j1 = s_list[base + 8 + g];
        float4 t0 = Tv[(rowbase + (size_t)j0) * 32 + lane];
        float4 n0 = nfv[(size_t)j0 * 32 + lane];
        float4 t1 = Tv[(rowbase + (size_t)j1) * 32 + lane];
        float4 n1 = nfv[(size_t)j1 * 32 + lane];
        acc.x += t0.x * n0.x; acc.y += t0.y * n0.y;
        acc.z += t0.z * n0.z; acc.w += t0.w * n0.w;
        acc.x += t1.x * n1.x; acc.y += t1.y * n1.y;
        acc.z += t1.z * n1.z; acc.w += t1.w * n1.w;
    }
    for (; base + 8 <= cnt; base += 8) {
        int j0 = s_list[base + g];
        float4 t0 = Tv[(rowbase + (size_t)j0) * 32 + lane];
        float4 n0 = nfv[(size_t)j0 * 32 + lane];
        acc.x += t0.x * n0.x; acc.y += t0.y * n0.y;
        acc.z += t0.z * n0.z; acc.w += t0.w * n0.w;
    }
    if (base + g < cnt) {                             // tail: first (cnt-base) groups
        int j0 = s_list[base + g];
        float4 t0 = Tv[(rowbase + (size_t)j0) * 32 + lane];
        float4 n0 = nfv[(size_t)j0 * 32 + lane];
        acc.x += t0.x * n0.x; acc.y += t0.y * n0.y;
        acc.z += t0.z * n0.z; acc.w += t0.w * n0.w;
    }

    reinterpret_cast<float4*>(&s_red[g][0])[lane] = acc;
    __syncthreads();

    if (tid < HDIM) {
        float s = 0.f;
        #pragma unroll
        for (int gg = 0; gg < 8; ++gg) s += s_red[gg][tid];
        s_agg[tid] = s;
    }
    __syncthreads();

    // ---- Phase 3: GRU matvecs. c-th row of w_* read as float4; agg/nf from
    // LDS broadcast (same address across lanes -> conflict-free).
    const float4* aggv = reinterpret_cast<const float4*>(s_agg);
    const float4* nfiv = reinterpret_cast<const float4*>(s_nfi);
    for (int c = tid; c < 3 * HDIM; c += 256) {
        const float4* wi = reinterpret_cast<const float4*>(w_ih + (size_t)c * HDIM);
        const float4* wh = reinterpret_cast<const float4*>(w_hh + (size_t)c * HDIM);
        float gs = 0.f, hs = 0.f;
        #pragma unroll 8
        for (int k = 0; k < HDIM / 4; ++k) {
            float4 w4 = wi[k]; float4 a4 = aggv[k];
            gs += w4.x * a4.x + w4.y * a4.y + w4.z * a4.z + w4.w * a4.w;
            float4 v4 = wh[k]; float4 n4 = nfiv[k];
            hs += v4.x * n4.x + v4.y * n4.y + v4.z * n4.z + v4.w * n4.w;
        }
        s_gi[c] = gs + b_ih[c];
        s_gh[c] = hs + b_hh[c];
    }
    __syncthreads();

    // ---- Phase 4: gates + output
    if (tid < HDIM) {
        float r  = 1.f / (1.f + expf(-(s_gi[tid] + s_gh[tid])));
        float z  = 1.f / (1.f + expf(-(s_gi[HDIM + tid] + s_gh[HDIM + tid])));
        float nn = tanhf(s_gi[2 * HDIM + tid] + r * s_gh[2 * HDIM + tid]);
        out[(size_t)i * HDIM + tid] = (1.f - z) * nn + z * s_nfi[tid];
    }
}

extern "C" void kernel_launch(void* const* d_in, const int* in_sizes, int n_in,
                              void* d_out, int out_size, void* d_ws, size_t ws_size,
                              hipStream_t stream) {
    const float* nf   = (const float*)d_in[0];
    const int*   adj  = (const int*)d_in[1];
    const float* T    = (const float*)d_in[2];
    const float* w_ih = (const float*)d_in[3];
    const float* w_hh = (const float*)d_in[4];
    const float* b_ih = (const float*)d_in[5];
    const float* b_hh = (const float*)d_in[6];
    float* out = (float*)d_out;

    motif_gru_kernel<<<dim3(N_NODES), dim3(256), 0, stream>>>(
        nf, adj, T, w_ih, w_hh, b_ih, b_hh, out);
}